// Round 1
// baseline (1393.838 us; speedup 1.0000x reference)
//
#include <hip/hip_runtime.h>
#include <hip/hip_bf16.h>
#include <stdint.h>

#define M_DIM 4096
#define N_DIM 8192
#define K_DIM 4096
#define EPS_F 1e-8f

typedef __attribute__((ext_vector_type(8))) __bf16 bf16x8;
typedef __attribute__((ext_vector_type(4))) __bf16 bf16x4;
typedef __attribute__((ext_vector_type(4))) float f32x4;

// async global->LDS, 16B per lane. LDS dest must be linear: wave base + lane*16.
#define GLD16(g, l) __builtin_amdgcn_global_load_lds( \
    (const __attribute__((address_space(1))) void*)(g), \
    (__attribute__((address_space(3))) void*)(l), 16, 0, 0)

// ---------------------------------------------------------------------------
// prep: one block per row (4096 x-rows then 8192 w-rows).
// Computes 1/max(||row||,eps) in fp32 and writes bf16 hi/lo split copies.
// ---------------------------------------------------------------------------
__global__ __launch_bounds__(256) void prep_kernel(
    const float* __restrict__ x, const float* __restrict__ w,
    __bf16* __restrict__ xhi, __bf16* __restrict__ xlo,
    __bf16* __restrict__ whi, __bf16* __restrict__ wlo,
    float* __restrict__ rxn, float* __restrict__ rwn) {
  int r = blockIdx.x;
  const float* src;
  __bf16 *hi, *lo;
  float* rn;
  if (r < M_DIM) {
    src = x + (size_t)r * K_DIM;
    hi = xhi + (size_t)r * K_DIM;
    lo = xlo + (size_t)r * K_DIM;
    rn = rxn + r;
  } else {
    int rr = r - M_DIM;
    src = w + (size_t)rr * K_DIM;
    hi = whi + (size_t)rr * K_DIM;
    lo = wlo + (size_t)rr * K_DIM;
    rn = rwn + rr;
  }
  int tid = threadIdx.x;
  float s = 0.f;
#pragma unroll
  for (int i = 0; i < 4; ++i) {
    int c = (i * 256 + tid) * 4;
    float4 v = *(const float4*)(src + c);
    s += v.x * v.x + v.y * v.y + v.z * v.z + v.w * v.w;
    float vv[4] = {v.x, v.y, v.z, v.w};
    bf16x4 h4, l4;
#pragma unroll
    for (int j = 0; j < 4; ++j) {
      __bf16 hj = (__bf16)vv[j];
      h4[j] = hj;
      l4[j] = (__bf16)(vv[j] - (float)hj);
    }
    *(bf16x4*)(hi + c) = h4;
    *(bf16x4*)(lo + c) = l4;
  }
  // wave reduce (64 lanes), then cross-wave via LDS
#pragma unroll
  for (int off = 32; off > 0; off >>= 1) s += __shfl_down(s, off);
  __shared__ float red[4];
  if ((tid & 63) == 0) red[tid >> 6] = s;
  __syncthreads();
  if (tid == 0) {
    float t = red[0] + red[1] + red[2] + red[3];
    *rn = 1.0f / fmaxf(sqrtf(t), EPS_F);
  }
}

// ---------------------------------------------------------------------------
// main GEMM: 128x128 tile, BK=64, 4 waves (2x2 of 64x64), 16x16x32 bf16 MFMA.
// K' = 3*4096 via segment pointer swap: hi*hi, hi*lo, lo*hi.
// ---------------------------------------------------------------------------
__global__ __launch_bounds__(256) void gemm_cos_kernel(
    const __bf16* __restrict__ xhi, const __bf16* __restrict__ xlo,
    const __bf16* __restrict__ whi, const __bf16* __restrict__ wlo,
    const float* __restrict__ rxn, const float* __restrict__ rwn,
    float* __restrict__ out) {
  __shared__ __align__(16) __bf16 As[128 * 64];
  __shared__ __align__(16) __bf16 Bs[128 * 64];

  int bid = blockIdx.x;
  // XCD-aware swizzle: 2048 blocks, 8 XCDs, 256 per XCD chunk (bijective).
  int swz = (bid & 7) * 256 + (bid >> 3);
  int bm = (swz >> 6) << 7;  // 32 M-tiles
  int bn = (swz & 63) << 7;  // 64 N-tiles

  int tid = threadIdx.x;
  int lane = tid & 63;
  int wid = tid >> 6;
  int wm = wid >> 1;  // 0..1
  int wn = wid & 1;   // 0..1

  f32x4 acc[4][4] = {};

  // staging addresses: thread t covers 8 contiguous bf16; 4 calls = 128x64 tile
  int sr = tid >> 3;           // row 0..31, +32 per call
  int sc = (tid & 7) * 8;      // col 0,8,..,56

  const __bf16* APS[3] = {xhi, xhi, xlo};
  const __bf16* BPS[3] = {whi, wlo, whi};

  __bf16* la = &As[tid * 8];
  __bf16* lb = &Bs[tid * 8];

  for (int seg = 0; seg < 3; ++seg) {
    const __bf16* pa = APS[seg] + (size_t)(bm + sr) * K_DIM + sc;
    const __bf16* pb = BPS[seg] + (size_t)(bn + sr) * K_DIM + sc;
    for (int kt = 0; kt < K_DIM; kt += 64) {
#pragma unroll
      for (int c = 0; c < 4; ++c) {
        GLD16(pa + (size_t)c * 32 * K_DIM + kt, la + c * 2048);
        GLD16(pb + (size_t)c * 32 * K_DIM + kt, lb + c * 2048);
      }
      __syncthreads();
#pragma unroll
      for (int kk = 0; kk < 2; ++kk) {
        bf16x8 af[4], bg[4];
        int klo = kk * 32 + (lane >> 4) * 8;
        int ar = wm * 64 + (lane & 15);
        int br = wn * 64 + (lane & 15);
#pragma unroll
        for (int i = 0; i < 4; ++i)
          af[i] = *(const bf16x8*)&As[(ar + i * 16) * 64 + klo];
#pragma unroll
        for (int i = 0; i < 4; ++i)
          bg[i] = *(const bf16x8*)&Bs[(br + i * 16) * 64 + klo];
#pragma unroll
        for (int mi = 0; mi < 4; ++mi)
#pragma unroll
          for (int ni = 0; ni < 4; ++ni)
            acc[mi][ni] = __builtin_amdgcn_mfma_f32_16x16x32_bf16(
                af[mi], bg[ni], acc[mi][ni], 0, 0, 0);
      }
      __syncthreads();
    }
  }

  // epilogue: out[r][c] = acc * rxn[r] * rwn[c]
  int ocol = bn + wn * 64 + (lane & 15);
  int orow0 = bm + wm * 64 + ((lane >> 4) << 2);
  float rw[4];
#pragma unroll
  for (int ni = 0; ni < 4; ++ni) rw[ni] = rwn[ocol + ni * 16];
#pragma unroll
  for (int mi = 0; mi < 4; ++mi) {
#pragma unroll
    for (int j = 0; j < 4; ++j) {
      int r = orow0 + mi * 16 + j;
      float rx = rxn[r];
#pragma unroll
      for (int ni = 0; ni < 4; ++ni)
        out[(size_t)r * N_DIM + ocol + ni * 16] = acc[mi][ni][j] * rx * rw[ni];
    }
  }
}

// ---------------------------------------------------------------------------
// fallback (ws too small): fp32 norms + fp32 LDS-tiled GEMM. Correct, slow.
// ---------------------------------------------------------------------------
__global__ __launch_bounds__(256) void fb_norms_kernel(
    const float* __restrict__ x, const float* __restrict__ w,
    float* __restrict__ rxn, float* __restrict__ rwn) {
  int r = blockIdx.x;
  const float* src = (r < M_DIM) ? x + (size_t)r * K_DIM
                                 : w + (size_t)(r - M_DIM) * K_DIM;
  float* rn = (r < M_DIM) ? rxn + r : rwn + (r - M_DIM);
  int tid = threadIdx.x;
  float s = 0.f;
#pragma unroll
  for (int i = 0; i < 4; ++i) {
    int c = (i * 256 + tid) * 4;
    float4 v = *(const float4*)(src + c);
    s += v.x * v.x + v.y * v.y + v.z * v.z + v.w * v.w;
  }
#pragma unroll
  for (int off = 32; off > 0; off >>= 1) s += __shfl_down(s, off);
  __shared__ float red[4];
  if ((tid & 63) == 0) red[tid >> 6] = s;
  __syncthreads();
  if (tid == 0) {
    float t = red[0] + red[1] + red[2] + red[3];
    *rn = 1.0f / fmaxf(sqrtf(t), EPS_F);
  }
}

__global__ __launch_bounds__(256) void fb_gemm_kernel(
    const float* __restrict__ x, const float* __restrict__ w,
    const float* __restrict__ rxn, const float* __restrict__ rwn,
    float* __restrict__ out) {
  __shared__ float As[64][17];
  __shared__ float Bs[64][17];
  int bm = blockIdx.y * 64, bn = blockIdx.x * 64;
  int tid = threadIdx.x;
  int tx = tid & 15, ty = tid >> 4;
  float acc[4][4] = {};
  for (int kt = 0; kt < K_DIM; kt += 16) {
#pragma unroll
    for (int i = 0; i < 4; ++i) {
      int e = i * 256 + tid;
      As[e >> 4][e & 15] = x[(size_t)(bm + (e >> 4)) * K_DIM + kt + (e & 15)];
      Bs[e >> 4][e & 15] = w[(size_t)(bn + (e >> 4)) * K_DIM + kt + (e & 15)];
    }
    __syncthreads();
#pragma unroll
    for (int k = 0; k < 16; ++k)
#pragma unroll
      for (int mi = 0; mi < 4; ++mi)
#pragma unroll
        for (int ni = 0; ni < 4; ++ni)
          acc[mi][ni] += As[ty * 4 + mi][k] * Bs[tx * 4 + ni][k];
    __syncthreads();
  }
#pragma unroll
  for (int mi = 0; mi < 4; ++mi) {
    int r = bm + ty * 4 + mi;
    float rx = rxn[r];
#pragma unroll
    for (int ni = 0; ni < 4; ++ni) {
      int c = bn + tx * 4 + ni;
      out[(size_t)r * N_DIM + c] = acc[mi][ni] * rx * rwn[c];
    }
  }
}

// ---------------------------------------------------------------------------
extern "C" void kernel_launch(void* const* d_in, const int* in_sizes, int n_in,
                              void* d_out, int out_size, void* d_ws, size_t ws_size,
                              hipStream_t stream) {
  const float* x = (const float*)d_in[0];
  const float* w = (const float*)d_in[1];
  float* out = (float*)d_out;
  char* ws = (char*)d_ws;

  float* rxn = (float*)ws;                        // 16 KiB
  float* rwn = (float*)(ws + (16 << 10));         // 32 KiB
  const size_t base = 64 << 10;
  const size_t xelems = (size_t)M_DIM * K_DIM;    // 16M
  const size_t welems = (size_t)N_DIM * K_DIM;    // 32M
  const size_t need = base + 2 * (xelems + welems) * sizeof(__bf16);

  if (ws_size >= need) {
    __bf16* xhi = (__bf16*)(ws + base);
    __bf16* xlo = xhi + xelems;
    __bf16* whi = xlo + xelems;
    __bf16* wlo = whi + welems;
    prep_kernel<<<M_DIM + N_DIM, 256, 0, stream>>>(x, w, xhi, xlo, whi, wlo,
                                                   rxn, rwn);
    gemm_cos_kernel<<<2048, 256, 0, stream>>>(xhi, xlo, whi, wlo, rxn, rwn, out);
  } else {
    fb_norms_kernel<<<M_DIM + N_DIM, 256, 0, stream>>>(x, w, rxn, rwn);
    fb_gemm_kernel<<<dim3(N_DIM / 64, M_DIM / 64), 256, 0, stream>>>(
        x, w, rxn, rwn, out);
  }
}

// Round 2
// 1016.902 us; speedup vs baseline: 1.3707x; 1.3707x over previous
//
#include <hip/hip_runtime.h>
#include <hip/hip_bf16.h>
#include <stdint.h>

#define M_DIM 4096
#define N_DIM 8192
#define K_DIM 4096
#define EPS_F 1e-8f

typedef __attribute__((ext_vector_type(8))) __bf16 bf16x8;
typedef __attribute__((ext_vector_type(4))) __bf16 bf16x4;
typedef __attribute__((ext_vector_type(4))) float f32x4;

// async global->LDS, 16B per lane. LDS dest must be linear: wave base + lane*16.
#define GLD16(g, l) __builtin_amdgcn_global_load_lds( \
    (const __attribute__((address_space(1))) void*)(g), \
    (__attribute__((address_space(3))) void*)(l), 16, 0, 0)

// raw barrier (no vmcnt drain) + compiler-only memory fence so LDS ops can't
// be reordered across it (llvm.amdgcn.s.barrier is not an IR memory fence).
#define BARRIER() do { asm volatile("" ::: "memory"); \
  __builtin_amdgcn_s_barrier(); asm volatile("" ::: "memory"); } while (0)

// ---------------------------------------------------------------------------
// prep: one block per row (4096 x-rows then 8192 w-rows).
// Computes 1/max(||row||,eps) in fp32 and writes bf16 hi/lo split copies.
// ---------------------------------------------------------------------------
__global__ __launch_bounds__(256) void prep_kernel(
    const float* __restrict__ x, const float* __restrict__ w,
    __bf16* __restrict__ xhi, __bf16* __restrict__ xlo,
    __bf16* __restrict__ whi, __bf16* __restrict__ wlo,
    float* __restrict__ rxn, float* __restrict__ rwn) {
  int r = blockIdx.x;
  const float* src;
  __bf16 *hi, *lo;
  float* rn;
  if (r < M_DIM) {
    src = x + (size_t)r * K_DIM;
    hi = xhi + (size_t)r * K_DIM;
    lo = xlo + (size_t)r * K_DIM;
    rn = rxn + r;
  } else {
    int rr = r - M_DIM;
    src = w + (size_t)rr * K_DIM;
    hi = whi + (size_t)rr * K_DIM;
    lo = wlo + (size_t)rr * K_DIM;
    rn = rwn + rr;
  }
  int tid = threadIdx.x;
  float s = 0.f;
#pragma unroll
  for (int i = 0; i < 4; ++i) {
    int c = (i * 256 + tid) * 4;
    float4 v = *(const float4*)(src + c);
    s += v.x * v.x + v.y * v.y + v.z * v.z + v.w * v.w;
    float vv[4] = {v.x, v.y, v.z, v.w};
    bf16x4 h4, l4;
#pragma unroll
    for (int j = 0; j < 4; ++j) {
      __bf16 hj = (__bf16)vv[j];
      h4[j] = hj;
      l4[j] = (__bf16)(vv[j] - (float)hj);
    }
    *(bf16x4*)(hi + c) = h4;
    *(bf16x4*)(lo + c) = l4;
  }
#pragma unroll
  for (int off = 32; off > 0; off >>= 1) s += __shfl_down(s, off);
  __shared__ float red[4];
  if ((tid & 63) == 0) red[tid >> 6] = s;
  __syncthreads();
  if (tid == 0) {
    float t = red[0] + red[1] + red[2] + red[3];
    *rn = 1.0f / fmaxf(sqrtf(t), EPS_F);
  }
}

// ---------------------------------------------------------------------------
// GEMM: 256x256 tile, BK=32, 4-buffer LDS ring, 8 waves (2M x 4N), 2 phases
// per K-tile, counted vmcnt(8), setprio around MFMA, XOR-swizzled LDS.
// K' = 3*4096 via segment pointer swap: hi*hi, hi*lo, lo*hi.
// ---------------------------------------------------------------------------
__global__ __launch_bounds__(512, 2) void gemm_cos_kernel(
    const __bf16* __restrict__ xhi, const __bf16* __restrict__ xlo,
    const __bf16* __restrict__ whi, const __bf16* __restrict__ wlo,
    const float* __restrict__ rxn, const float* __restrict__ rwn,
    float* __restrict__ out) {
  // per buffer (32 KB): A rows 0..255 at [0,16K) (row*64B), B rows at [16K,32K)
  __shared__ __align__(16) char lds[131072];

  const int tid = threadIdx.x;
  const int lane = tid & 63;
  const int wid = tid >> 6;
  const int wm = wid >> 2;  // 0..1  (M half: 128 rows)
  const int wn = wid & 3;   // 0..3  (N quarter: 64 cols)

  int bid = blockIdx.x;
  int swz = (bid & 7) * 64 + (bid >> 3);  // 512 blocks, 8 XCDs, bijective
  const int bm = (swz >> 5) << 8;  // 16 M-tiles
  const int bn = (swz & 31) << 8;  // 32 N-tiles

  // ---- staging geometry: half-tile = 128 rows x 32 K-cols (64B/row)
  // thread t: row = t>>2, LDS slot = t&3 (linear dest), global chunk =
  // slot ^ ((row>>1)&3)  (inverse of the read-side swizzle)
  const int srow = tid >> 2;
  const int scsrc = (tid & 3) ^ ((srow >> 1) & 3);
  const size_t a0_off = (size_t)(bm + srow) * K_DIM + scsrc * 8;
  const size_t a1_off = (size_t)(bm + 128 + srow) * K_DIM + scsrc * 8;
  const size_t b0_off = (size_t)(bn + srow) * K_DIM + scsrc * 8;
  const size_t b1_off = (size_t)(bn + 128 + srow) * K_DIM + scsrc * 8;

  char* const lds_my = lds + tid * 16;

  // ---- read geometry: frag row r, k-chunk j=lane>>4
  // byte = base + r*64 + ((j ^ ((r>>1)&3)) << 4)
  const int j16 = lane >> 4;
  const int arow_base = wm * 128 + (lane & 15);
  const int brow_base = wn * 64 + (lane & 15);

  f32x4 acc[8][4] = {};

  const int NT = 3 * (K_DIM / 32);  // 384

#define STAGE_A(s) do { int s_ = (s); \
    const __bf16* base_ = (s_ < 256) ? xhi : xlo; \
    size_t kt_ = (size_t)(s_ & 127) * 32; \
    char* d_ = lds_my + (size_t)(s_ & 3) * 32768; \
    GLD16(base_ + a0_off + kt_, d_); \
    GLD16(base_ + a1_off + kt_, d_ + 8192); } while (0)

#define STAGE_B(s) do { int s_ = (s); \
    const __bf16* base_ = ((s_ >> 7) == 1) ? wlo : whi; \
    size_t kt_ = (size_t)(s_ & 127) * 32; \
    char* d_ = lds_my + (size_t)(s_ & 3) * 32768; \
    GLD16(base_ + b0_off + kt_, d_ + 16384); \
    GLD16(base_ + b1_off + kt_, d_ + 24576); } while (0)

  // prologue: stage tiles 0,1,2 (12 loads/thread); wait so tile 0 landed
  STAGE_A(0); STAGE_B(0);
  STAGE_A(1); STAGE_B(1);
  STAGE_A(2); STAGE_B(2);
  asm volatile("s_waitcnt vmcnt(8)" ::: "memory");
  BARRIER();

  for (int T = 0; T < NT; ++T) {
    char* buf = lds + (size_t)(T & 3) * 32768;
    const bool stg = (T + 3 < NT);

    bf16x8 af[4], bg[4];

    // ---------- phase A (Msub=0): 8 ds_read_b128 + stage A-halves ----------
#pragma unroll
    for (int mi = 0; mi < 4; ++mi) {
      int r = arow_base + mi * 16;
      af[mi] = *(const bf16x8*)(buf + r * 64 + ((j16 ^ ((r >> 1) & 3)) << 4));
    }
#pragma unroll
    for (int ni = 0; ni < 4; ++ni) {
      int r = brow_base + ni * 16;
      bg[ni] = *(const bf16x8*)(buf + 16384 + r * 64 +
                                ((j16 ^ ((r >> 1) & 3)) << 4));
    }
    if (stg) STAGE_A(T + 3);
    BARRIER();
    __builtin_amdgcn_s_setprio(1);
#pragma unroll
    for (int mi = 0; mi < 4; ++mi)
#pragma unroll
      for (int ni = 0; ni < 4; ++ni)
        acc[mi][ni] = __builtin_amdgcn_mfma_f32_16x16x32_bf16(
            af[mi], bg[ni], acc[mi][ni], 0, 0, 0);
    __builtin_amdgcn_s_setprio(0);
    BARRIER();

    // ---------- phase B (Msub=1): 4 ds_read_b128 (B-frags reused) ----------
#pragma unroll
    for (int mi = 0; mi < 4; ++mi) {
      int r = arow_base + 64 + mi * 16;
      af[mi] = *(const bf16x8*)(buf + r * 64 + ((j16 ^ ((r >> 1) & 3)) << 4));
    }
    if (stg) STAGE_B(T + 3);
    BARRIER();
    __builtin_amdgcn_s_setprio(1);
#pragma unroll
    for (int mi = 0; mi < 4; ++mi)
#pragma unroll
      for (int ni = 0; ni < 4; ++ni)
        acc[4 + mi][ni] = __builtin_amdgcn_mfma_f32_16x16x32_bf16(
            af[mi], bg[ni], acc[4 + mi][ni], 0, 0, 0);
    __builtin_amdgcn_s_setprio(0);

    // ---------- K-tile boundary: counted wait (never 0 in steady state) ----
    if (T < NT - 3) {
      asm volatile("s_waitcnt vmcnt(8)" ::: "memory");
    } else if (T == NT - 3) {
      asm volatile("s_waitcnt vmcnt(4)" ::: "memory");
    } else if (T == NT - 2) {
      asm volatile("s_waitcnt vmcnt(0)" ::: "memory");
    }
    BARRIER();
  }

  // ---------- epilogue: out[r][c] = acc * rxn[r] * rwn[c] ----------
  const int ocol = bn + wn * 64 + (lane & 15);
  const int orow0 = bm + wm * 128 + ((lane >> 4) << 2);
  float rw[4];
#pragma unroll
  for (int ni = 0; ni < 4; ++ni) rw[ni] = rwn[ocol + ni * 16];
#pragma unroll
  for (int m = 0; m < 8; ++m) {
#pragma unroll
    for (int jj = 0; jj < 4; ++jj) {
      int r = orow0 + m * 16 + jj;
      float rx = rxn[r];
#pragma unroll
      for (int ni = 0; ni < 4; ++ni)
        out[(size_t)r * N_DIM + ocol + ni * 16] = acc[m][ni][jj] * rx * rw[ni];
    }
  }
#undef STAGE_A
#undef STAGE_B
}

// ---------------------------------------------------------------------------
// fallback (ws too small): fp32 norms + fp32 LDS-tiled GEMM. Correct, slow.
// ---------------------------------------------------------------------------
__global__ __launch_bounds__(256) void fb_norms_kernel(
    const float* __restrict__ x, const float* __restrict__ w,
    float* __restrict__ rxn, float* __restrict__ rwn) {
  int r = blockIdx.x;
  const float* src = (r < M_DIM) ? x + (size_t)r * K_DIM
                                 : w + (size_t)(r - M_DIM) * K_DIM;
  float* rn = (r < M_DIM) ? rxn + r : rwn + (r - M_DIM);
  int tid = threadIdx.x;
  float s = 0.f;
#pragma unroll
  for (int i = 0; i < 4; ++i) {
    int c = (i * 256 + tid) * 4;
    float4 v = *(const float4*)(src + c);
    s += v.x * v.x + v.y * v.y + v.z * v.z + v.w * v.w;
  }
#pragma unroll
  for (int off = 32; off > 0; off >>= 1) s += __shfl_down(s, off);
  __shared__ float red[4];
  if ((tid & 63) == 0) red[tid >> 6] = s;
  __syncthreads();
  if (tid == 0) {
    float t = red[0] + red[1] + red[2] + red[3];
    *rn = 1.0f / fmaxf(sqrtf(t), EPS_F);
  }
}

__global__ __launch_bounds__(256) void fb_gemm_kernel(
    const float* __restrict__ x, const float* __restrict__ w,
    const float* __restrict__ rxn, const float* __restrict__ rwn,
    float* __restrict__ out) {
  __shared__ float As[64][17];
  __shared__ float Bs[64][17];
  int bm = blockIdx.y * 64, bn = blockIdx.x * 64;
  int tid = threadIdx.x;
  int tx = tid & 15, ty = tid >> 4;
  float acc[4][4] = {};
  for (int kt = 0; kt < K_DIM; kt += 16) {
#pragma unroll
    for (int i = 0; i < 4; ++i) {
      int e = i * 256 + tid;
      As[e >> 4][e & 15] = x[(size_t)(bm + (e >> 4)) * K_DIM + kt + (e & 15)];
      Bs[e >> 4][e & 15] = w[(size_t)(bn + (e >> 4)) * K_DIM + kt + (e & 15)];
    }
    __syncthreads();
#pragma unroll
    for (int k = 0; k < 16; ++k)
#pragma unroll
      for (int mi = 0; mi < 4; ++mi)
#pragma unroll
        for (int ni = 0; ni < 4; ++ni)
          acc[mi][ni] += As[ty * 4 + mi][k] * Bs[tx * 4 + ni][k];
    __syncthreads();
  }
#pragma unroll
  for (int mi = 0; mi < 4; ++mi) {
    int r = bm + ty * 4 + mi;
    float rx = rxn[r];
#pragma unroll
    for (int ni = 0; ni < 4; ++ni) {
      int c = bn + tx * 4 + ni;
      out[(size_t)r * N_DIM + c] = acc[mi][ni] * rx * rwn[c];
    }
  }
}

// ---------------------------------------------------------------------------
extern "C" void kernel_launch(void* const* d_in, const int* in_sizes, int n_in,
                              void* d_out, int out_size, void* d_ws, size_t ws_size,
                              hipStream_t stream) {
  const float* x = (const float*)d_in[0];
  const float* w = (const float*)d_in[1];
  float* out = (float*)d_out;
  char* ws = (char*)d_ws;

  float* rxn = (float*)ws;                 // 16 KiB
  float* rwn = (float*)(ws + (16 << 10));  // 32 KiB
  const size_t base = 64 << 10;
  const size_t xelems = (size_t)M_DIM * K_DIM;  // 16M
  const size_t welems = (size_t)N_DIM * K_DIM;  // 32M
  const size_t need = base + 2 * (xelems + welems) * sizeof(__bf16);

  if (ws_size >= need) {
    __bf16* xhi = (__bf16*)(ws + base);
    __bf16* xlo = xhi + xelems;
    __bf16* whi = xlo + xelems;
    __bf16* wlo = whi + welems;
    prep_kernel<<<M_DIM + N_DIM, 256, 0, stream>>>(x, w, xhi, xlo, whi, wlo,
                                                   rxn, rwn);
    gemm_cos_kernel<<<512, 512, 0, stream>>>(xhi, xlo, whi, wlo, rxn, rwn, out);
  } else {
    fb_norms_kernel<<<M_DIM + N_DIM, 256, 0, stream>>>(x, w, rxn, rwn);
    fb_gemm_kernel<<<dim3(N_DIM / 64, M_DIM / 64), 256, 0, stream>>>(
        x, w, rxn, rwn, out);
  }
}

// Round 3
// 533.768 us; speedup vs baseline: 2.6113x; 1.9051x over previous
//
#include <hip/hip_runtime.h>
#include <hip/hip_bf16.h>
#include <stdint.h>

#define M_DIM 4096
#define N_DIM 8192
#define K_DIM 4096
#define EPS_F 1e-8f

typedef __attribute__((ext_vector_type(8))) _Float16 f16x8;
typedef __attribute__((ext_vector_type(4))) float f32x4;

// async global->LDS, 16B per lane. LDS dest must be linear: wave base + lane*16.
#define GLD16(g, l) __builtin_amdgcn_global_load_lds( \
    (const __attribute__((address_space(1))) void*)(g), \
    (__attribute__((address_space(3))) void*)(l), 16, 0, 0)

// raw barrier (no vmcnt drain) + compiler-only memory fence so LDS ops can't
// be reordered across it (llvm.amdgcn.s.barrier is not an IR memory fence).
#define BARRIER() do { asm volatile("" ::: "memory"); \
  __builtin_amdgcn_s_barrier(); asm volatile("" ::: "memory"); } while (0)

// ---------------------------------------------------------------------------
// prep: one block per row (4096 x-rows then 8192 w-rows).
// Computes 1/max(||row||,eps) in fp32 (from the ORIGINAL fp32 data) and
// writes an fp16 copy of the row (single-GEMM scheme; cross terms dropped,
// cos-error ~3e-5 max, see round-3 analysis).
// ---------------------------------------------------------------------------
__global__ __launch_bounds__(256) void prep_kernel(
    const float* __restrict__ x, const float* __restrict__ w,
    _Float16* __restrict__ xh, _Float16* __restrict__ wh,
    float* __restrict__ rxn, float* __restrict__ rwn) {
  int r = blockIdx.x;
  const float* src;
  _Float16* dst;
  float* rn;
  if (r < M_DIM) {
    src = x + (size_t)r * K_DIM;
    dst = xh + (size_t)r * K_DIM;
    rn = rxn + r;
  } else {
    int rr = r - M_DIM;
    src = w + (size_t)rr * K_DIM;
    dst = wh + (size_t)rr * K_DIM;
    rn = rwn + rr;
  }
  int tid = threadIdx.x;
  float s = 0.f;
#pragma unroll
  for (int i = 0; i < 2; ++i) {
    int c = (i * 256 + tid) * 8;
    float4 v0 = *(const float4*)(src + c);
    float4 v1 = *(const float4*)(src + c + 4);
    s += v0.x * v0.x + v0.y * v0.y + v0.z * v0.z + v0.w * v0.w;
    s += v1.x * v1.x + v1.y * v1.y + v1.z * v1.z + v1.w * v1.w;
    f16x8 h;
    h[0] = (_Float16)v0.x; h[1] = (_Float16)v0.y;
    h[2] = (_Float16)v0.z; h[3] = (_Float16)v0.w;
    h[4] = (_Float16)v1.x; h[5] = (_Float16)v1.y;
    h[6] = (_Float16)v1.z; h[7] = (_Float16)v1.w;
    *(f16x8*)(dst + c) = h;
  }
#pragma unroll
  for (int off = 32; off > 0; off >>= 1) s += __shfl_down(s, off);
  __shared__ float red[4];
  if ((tid & 63) == 0) red[tid >> 6] = s;
  __syncthreads();
  if (tid == 0) {
    float t = red[0] + red[1] + red[2] + red[3];
    *rn = 1.0f / fmaxf(sqrtf(t), EPS_F);
  }
}

// ---------------------------------------------------------------------------
// GEMM: 256x256 tile, BK=32, 4-buffer LDS ring, 8 waves (2M x 4N), 2 phases
// per K-tile, counted vmcnt(8), setprio around MFMA, XOR-swizzled LDS.
// Single fp16 GEMM over K=4096 (NT=128).
// ---------------------------------------------------------------------------
__global__ __launch_bounds__(512, 2) void gemm_cos_kernel(
    const _Float16* __restrict__ xh, const _Float16* __restrict__ wh,
    const float* __restrict__ rxn, const float* __restrict__ rwn,
    float* __restrict__ out) {
  // per buffer (32 KB): A rows 0..255 at [0,16K) (row*64B), B rows at [16K,32K)
  __shared__ __align__(16) char lds[131072];

  const int tid = threadIdx.x;
  const int lane = tid & 63;
  const int wid = tid >> 6;
  const int wm = wid >> 2;  // 0..1  (M half: 128 rows)
  const int wn = wid & 3;   // 0..3  (N quarter: 64 cols)

  int bid = blockIdx.x;
  int swz = (bid & 7) * 64 + (bid >> 3);  // 512 blocks, 8 XCDs, bijective
  const int bm = (swz >> 5) << 8;  // 16 M-tiles
  const int bn = (swz & 31) << 8;  // 32 N-tiles

  // ---- staging geometry: half-tile = 128 rows x 32 K-cols (64B/row)
  // thread t: row = t>>2, LDS slot = t&3 (linear dest), global chunk =
  // slot ^ ((row>>1)&3)  (inverse of the read-side swizzle)
  const int srow = tid >> 2;
  const int scsrc = (tid & 3) ^ ((srow >> 1) & 3);
  const size_t a0_off = (size_t)(bm + srow) * K_DIM + scsrc * 8;
  const size_t a1_off = (size_t)(bm + 128 + srow) * K_DIM + scsrc * 8;
  const size_t b0_off = (size_t)(bn + srow) * K_DIM + scsrc * 8;
  const size_t b1_off = (size_t)(bn + 128 + srow) * K_DIM + scsrc * 8;

  char* const lds_my = lds + tid * 16;

  // ---- read geometry: frag row r, k-chunk j=lane>>4
  // byte = base + r*64 + ((j ^ ((r>>1)&3)) << 4)
  const int j16 = lane >> 4;
  const int arow_base = wm * 128 + (lane & 15);
  const int brow_base = wn * 64 + (lane & 15);

  f32x4 acc[8][4] = {};

  const int NT = K_DIM / 32;  // 128

#define STAGE_A(s) do { int s_ = (s); \
    size_t kt_ = (size_t)s_ * 32; \
    char* d_ = lds_my + (size_t)(s_ & 3) * 32768; \
    GLD16(xh + a0_off + kt_, d_); \
    GLD16(xh + a1_off + kt_, d_ + 8192); } while (0)

#define STAGE_B(s) do { int s_ = (s); \
    size_t kt_ = (size_t)s_ * 32; \
    char* d_ = lds_my + (size_t)(s_ & 3) * 32768; \
    GLD16(wh + b0_off + kt_, d_ + 16384); \
    GLD16(wh + b1_off + kt_, d_ + 24576); } while (0)

  // prologue: stage tiles 0,1,2 (12 loads/thread); wait so tile 0 landed
  STAGE_A(0); STAGE_B(0);
  STAGE_A(1); STAGE_B(1);
  STAGE_A(2); STAGE_B(2);
  asm volatile("s_waitcnt vmcnt(8)" ::: "memory");
  BARRIER();

  for (int T = 0; T < NT; ++T) {
    char* buf = lds + (size_t)(T & 3) * 32768;
    const bool stg = (T + 3 < NT);

    f16x8 af[4], bg[4];

    // ---------- phase A (Msub=0): 8 ds_read_b128 + stage A-halves ----------
#pragma unroll
    for (int mi = 0; mi < 4; ++mi) {
      int r = arow_base + mi * 16;
      af[mi] = *(const f16x8*)(buf + r * 64 + ((j16 ^ ((r >> 1) & 3)) << 4));
    }
#pragma unroll
    for (int ni = 0; ni < 4; ++ni) {
      int r = brow_base + ni * 16;
      bg[ni] = *(const f16x8*)(buf + 16384 + r * 64 +
                               ((j16 ^ ((r >> 1) & 3)) << 4));
    }
    if (stg) STAGE_A(T + 3);
    BARRIER();
    __builtin_amdgcn_s_setprio(1);
#pragma unroll
    for (int mi = 0; mi < 4; ++mi)
#pragma unroll
      for (int ni = 0; ni < 4; ++ni)
        acc[mi][ni] = __builtin_amdgcn_mfma_f32_16x16x32_f16(
            af[mi], bg[ni], acc[mi][ni], 0, 0, 0);
    __builtin_amdgcn_s_setprio(0);
    BARRIER();

    // ---------- phase B (Msub=1): 4 ds_read_b128 (B-frags reused) ----------
#pragma unroll
    for (int mi = 0; mi < 4; ++mi) {
      int r = arow_base + 64 + mi * 16;
      af[mi] = *(const f16x8*)(buf + r * 64 + ((j16 ^ ((r >> 1) & 3)) << 4));
    }
    if (stg) STAGE_B(T + 3);
    BARRIER();
    __builtin_amdgcn_s_setprio(1);
#pragma unroll
    for (int mi = 0; mi < 4; ++mi)
#pragma unroll
      for (int ni = 0; ni < 4; ++ni)
        acc[4 + mi][ni] = __builtin_amdgcn_mfma_f32_16x16x32_f16(
            af[mi], bg[ni], acc[4 + mi][ni], 0, 0, 0);
    __builtin_amdgcn_s_setprio(0);

    // ---------- K-tile boundary: counted wait (never 0 in steady state) ----
    if (T < NT - 3) {
      asm volatile("s_waitcnt vmcnt(8)" ::: "memory");
    } else if (T == NT - 3) {
      asm volatile("s_waitcnt vmcnt(4)" ::: "memory");
    } else if (T == NT - 2) {
      asm volatile("s_waitcnt vmcnt(0)" ::: "memory");
    }
    BARRIER();
  }

  // ---------- epilogue: out[r][c] = acc * rxn[r] * rwn[c] ----------
  const int ocol = bn + wn * 64 + (lane & 15);
  const int orow0 = bm + wm * 128 + ((lane >> 4) << 2);
  float rw[4];
#pragma unroll
  for (int ni = 0; ni < 4; ++ni) rw[ni] = rwn[ocol + ni * 16];
#pragma unroll
  for (int m = 0; m < 8; ++m) {
#pragma unroll
    for (int jj = 0; jj < 4; ++jj) {
      int r = orow0 + m * 16 + jj;
      float rx = rxn[r];
#pragma unroll
      for (int ni = 0; ni < 4; ++ni)
        out[(size_t)r * N_DIM + ocol + ni * 16] = acc[m][ni][jj] * rx * rw[ni];
    }
  }
#undef STAGE_A
#undef STAGE_B
}

// ---------------------------------------------------------------------------
// fallback (ws too small): fp32 norms + fp32 LDS-tiled GEMM. Correct, slow.
// ---------------------------------------------------------------------------
__global__ __launch_bounds__(256) void fb_norms_kernel(
    const float* __restrict__ x, const float* __restrict__ w,
    float* __restrict__ rxn, float* __restrict__ rwn) {
  int r = blockIdx.x;
  const float* src = (r < M_DIM) ? x + (size_t)r * K_DIM
                                 : w + (size_t)(r - M_DIM) * K_DIM;
  float* rn = (r < M_DIM) ? rxn + r : rwn + (r - M_DIM);
  int tid = threadIdx.x;
  float s = 0.f;
#pragma unroll
  for (int i = 0; i < 4; ++i) {
    int c = (i * 256 + tid) * 4;
    float4 v = *(const float4*)(src + c);
    s += v.x * v.x + v.y * v.y + v.z * v.z + v.w * v.w;
  }
#pragma unroll
  for (int off = 32; off > 0; off >>= 1) s += __shfl_down(s, off);
  __shared__ float red[4];
  if ((tid & 63) == 0) red[tid >> 6] = s;
  __syncthreads();
  if (tid == 0) {
    float t = red[0] + red[1] + red[2] + red[3];
    *rn = 1.0f / fmaxf(sqrtf(t), EPS_F);
  }
}

__global__ __launch_bounds__(256) void fb_gemm_kernel(
    const float* __restrict__ x, const float* __restrict__ w,
    const float* __restrict__ rxn, const float* __restrict__ rwn,
    float* __restrict__ out) {
  __shared__ float As[64][17];
  __shared__ float Bs[64][17];
  int bm = blockIdx.y * 64, bn = blockIdx.x * 64;
  int tid = threadIdx.x;
  int tx = tid & 15, ty = tid >> 4;
  float acc[4][4] = {};
  for (int kt = 0; kt < K_DIM; kt += 16) {
#pragma unroll
    for (int i = 0; i < 4; ++i) {
      int e = i * 256 + tid;
      As[e >> 4][e & 15] = x[(size_t)(bm + (e >> 4)) * K_DIM + kt + (e & 15)];
      Bs[e >> 4][e & 15] = w[(size_t)(bn + (e >> 4)) * K_DIM + kt + (e & 15)];
    }
    __syncthreads();
#pragma unroll
    for (int k = 0; k < 16; ++k)
#pragma unroll
      for (int mi = 0; mi < 4; ++mi)
#pragma unroll
        for (int ni = 0; ni < 4; ++ni)
          acc[mi][ni] += As[ty * 4 + mi][k] * Bs[tx * 4 + ni][k];
    __syncthreads();
  }
#pragma unroll
  for (int mi = 0; mi < 4; ++mi) {
    int r = bm + ty * 4 + mi;
    float rx = rxn[r];
#pragma unroll
    for (int ni = 0; ni < 4; ++ni) {
      int c = bn + tx * 4 + ni;
      out[(size_t)r * N_DIM + c] = acc[mi][ni] * rx * rwn[c];
    }
  }
}

// ---------------------------------------------------------------------------
extern "C" void kernel_launch(void* const* d_in, const int* in_sizes, int n_in,
                              void* d_out, int out_size, void* d_ws, size_t ws_size,
                              hipStream_t stream) {
  const float* x = (const float*)d_in[0];
  const float* w = (const float*)d_in[1];
  float* out = (float*)d_out;
  char* ws = (char*)d_ws;

  float* rxn = (float*)ws;                 // 16 KiB
  float* rwn = (float*)(ws + (16 << 10));  // 32 KiB
  const size_t base = 64 << 10;
  const size_t xelems = (size_t)M_DIM * K_DIM;  // 16M
  const size_t welems = (size_t)N_DIM * K_DIM;  // 32M
  const size_t need = base + (xelems + welems) * sizeof(_Float16);

  if (ws_size >= need) {
    _Float16* xh = (_Float16*)(ws + base);
    _Float16* wh = xh + xelems;
    prep_kernel<<<M_DIM + N_DIM, 256, 0, stream>>>(x, w, xh, wh, rxn, rwn);
    gemm_cos_kernel<<<512, 512, 0, stream>>>(xh, wh, rxn, rwn, out);
  } else {
    fb_norms_kernel<<<M_DIM + N_DIM, 256, 0, stream>>>(x, w, rxn, rwn);
    fb_gemm_kernel<<<dim3(N_DIM / 64, M_DIM / 64), 256, 0, stream>>>(
        x, w, rxn, rwn, out);
  }
}

// Round 5
// 528.474 us; speedup vs baseline: 2.6375x; 1.0100x over previous
//
#include <hip/hip_runtime.h>
#include <hip/hip_bf16.h>
#include <stdint.h>

#define M_DIM 4096
#define N_DIM 8192
#define K_DIM 4096
#define EPS_F 1e-8f

typedef __attribute__((ext_vector_type(8))) _Float16 f16x8;
typedef __attribute__((ext_vector_type(4))) _Float16 f16x4;
typedef __attribute__((ext_vector_type(4))) float f32x4;

// async global->LDS, 16B per lane. LDS dest must be linear: wave base + lane*16.
#define GLD16(g, l) __builtin_amdgcn_global_load_lds( \
    (const __attribute__((address_space(1))) void*)(g), \
    (__attribute__((address_space(3))) void*)(l), 16, 0, 0)

// raw barrier (no vmcnt drain) + compiler-only memory fence so LDS ops can't
// be reordered across it (llvm.amdgcn.s.barrier is not an IR memory fence).
#define BARRIER() do { asm volatile("" ::: "memory"); \
  __builtin_amdgcn_s_barrier(); asm volatile("" ::: "memory"); } while (0)

// ---------------------------------------------------------------------------
// prep: one block per row (4096 x-rows then 8192 w-rows). Each WAVE covers a
// quarter-row independently: fp32 read (1KB-contiguous per load instr),
// fp16 write (512B-contiguous), per-wave sumsq partial. No LDS, no barriers.
// ---------------------------------------------------------------------------
__global__ __launch_bounds__(256) void prep_kernel(
    const float* __restrict__ x, const float* __restrict__ w,
    _Float16* __restrict__ xh, _Float16* __restrict__ wh,
    float* __restrict__ partials) {
  int r = blockIdx.x;
  const float* src;
  _Float16* dst;
  if (r < M_DIM) {
    src = x + (size_t)r * K_DIM;
    dst = xh + (size_t)r * K_DIM;
  } else {
    int rr = r - M_DIM;
    src = w + (size_t)rr * K_DIM;
    dst = wh + (size_t)rr * K_DIM;
  }
  const int lane = threadIdx.x & 63;
  const int wv = threadIdx.x >> 6;
  const int base = wv * 1024;
  float s = 0.f;
#pragma unroll
  for (int i = 0; i < 4; ++i) {
    int c = base + i * 256 + lane * 4;
    float4 v = *(const float4*)(src + c);
    s += v.x * v.x + v.y * v.y + v.z * v.z + v.w * v.w;
    f16x4 h;
    h[0] = (_Float16)v.x; h[1] = (_Float16)v.y;
    h[2] = (_Float16)v.z; h[3] = (_Float16)v.w;
    *(f16x4*)(dst + c) = h;
  }
#pragma unroll
  for (int off = 32; off > 0; off >>= 1) s += __shfl_down(s, off);
  if (lane == 0) partials[r * 4 + wv] = s;
}

// finalize: rn[r] = 1/max(sqrt(sum of 4 partials), eps). 12288 threads.
__global__ __launch_bounds__(256) void finalize_kernel(
    const float* __restrict__ partials,
    float* __restrict__ rxn, float* __restrict__ rwn) {
  int r = blockIdx.x * 256 + threadIdx.x;
  f32x4 p = *(const f32x4*)(partials + (size_t)r * 4);
  float t = p[0] + p[1] + p[2] + p[3];
  float v = 1.0f / fmaxf(sqrtf(t), EPS_F);
  if (r < M_DIM) rxn[r] = v;
  else rwn[r - M_DIM] = v;
}

// ---------------------------------------------------------------------------
// GEMM: 256x256 tile, BK=32, 4-buffer LDS ring, 8 waves (2M x 4N), 2 phases
// per K-tile, counted vmcnt(8), setprio around MFMA, XOR-swizzled LDS.
// Single fp16 GEMM over K=4096 (NT=128).  [UNCHANGED from round 3]
// ---------------------------------------------------------------------------
__global__ __launch_bounds__(512, 2) void gemm_cos_kernel(
    const _Float16* __restrict__ xh, const _Float16* __restrict__ wh,
    const float* __restrict__ rxn, const float* __restrict__ rwn,
    float* __restrict__ out) {
  // per buffer (32 KB): A rows 0..255 at [0,16K) (row*64B), B rows at [16K,32K)
  __shared__ __align__(16) char lds[131072];

  const int tid = threadIdx.x;
  const int lane = tid & 63;
  const int wid = tid >> 6;
  const int wm = wid >> 2;  // 0..1  (M half: 128 rows)
  const int wn = wid & 3;   // 0..3  (N quarter: 64 cols)

  int bid = blockIdx.x;
  int swz = (bid & 7) * 64 + (bid >> 3);  // 512 blocks, 8 XCDs, bijective
  const int bm = (swz >> 5) << 8;  // 16 M-tiles
  const int bn = (swz & 31) << 8;  // 32 N-tiles

  // ---- staging geometry: half-tile = 128 rows x 32 K-cols (64B/row)
  // thread t: row = t>>2, LDS slot = t&3 (linear dest), global chunk =
  // slot ^ ((row>>1)&3)  (inverse of the read-side swizzle)
  const int srow = tid >> 2;
  const int scsrc = (tid & 3) ^ ((srow >> 1) & 3);
  const size_t a0_off = (size_t)(bm + srow) * K_DIM + scsrc * 8;
  const size_t a1_off = (size_t)(bm + 128 + srow) * K_DIM + scsrc * 8;
  const size_t b0_off = (size_t)(bn + srow) * K_DIM + scsrc * 8;
  const size_t b1_off = (size_t)(bn + 128 + srow) * K_DIM + scsrc * 8;

  char* const lds_my = lds + tid * 16;

  // ---- read geometry: frag row r, k-chunk j=lane>>4
  // byte = base + r*64 + ((j ^ ((r>>1)&3)) << 4)
  const int j16 = lane >> 4;
  const int arow_base = wm * 128 + (lane & 15);
  const int brow_base = wn * 64 + (lane & 15);

  f32x4 acc[8][4] = {};

  const int NT = K_DIM / 32;  // 128

#define STAGE_A(s) do { int s_ = (s); \
    size_t kt_ = (size_t)s_ * 32; \
    char* d_ = lds_my + (size_t)(s_ & 3) * 32768; \
    GLD16(xh + a0_off + kt_, d_); \
    GLD16(xh + a1_off + kt_, d_ + 8192); } while (0)

#define STAGE_B(s) do { int s_ = (s); \
    size_t kt_ = (size_t)s_ * 32; \
    char* d_ = lds_my + (size_t)(s_ & 3) * 32768; \
    GLD16(wh + b0_off + kt_, d_ + 16384); \
    GLD16(wh + b1_off + kt_, d_ + 24576); } while (0)

  // prologue: stage tiles 0,1,2 (12 loads/thread); wait so tile 0 landed
  STAGE_A(0); STAGE_B(0);
  STAGE_A(1); STAGE_B(1);
  STAGE_A(2); STAGE_B(2);
  asm volatile("s_waitcnt vmcnt(8)" ::: "memory");
  BARRIER();

  for (int T = 0; T < NT; ++T) {
    char* buf = lds + (size_t)(T & 3) * 32768;
    const bool stg = (T + 3 < NT);

    f16x8 af[4], bg[4];

    // ---------- phase A (Msub=0): 8 ds_read_b128 + stage A-halves ----------
#pragma unroll
    for (int mi = 0; mi < 4; ++mi) {
      int r = arow_base + mi * 16;
      af[mi] = *(const f16x8*)(buf + r * 64 + ((j16 ^ ((r >> 1) & 3)) << 4));
    }
#pragma unroll
    for (int ni = 0; ni < 4; ++ni) {
      int r = brow_base + ni * 16;
      bg[ni] = *(const f16x8*)(buf + 16384 + r * 64 +
                               ((j16 ^ ((r >> 1) & 3)) << 4));
    }
    if (stg) STAGE_A(T + 3);
    BARRIER();
    __builtin_amdgcn_s_setprio(1);
#pragma unroll
    for (int mi = 0; mi < 4; ++mi)
#pragma unroll
      for (int ni = 0; ni < 4; ++ni)
        acc[mi][ni] = __builtin_amdgcn_mfma_f32_16x16x32_f16(
            af[mi], bg[ni], acc[mi][ni], 0, 0, 0);
    __builtin_amdgcn_s_setprio(0);
    BARRIER();

    // ---------- phase B (Msub=1): 4 ds_read_b128 (B-frags reused) ----------
#pragma unroll
    for (int mi = 0; mi < 4; ++mi) {
      int r = arow_base + 64 + mi * 16;
      af[mi] = *(const f16x8*)(buf + r * 64 + ((j16 ^ ((r >> 1) & 3)) << 4));
    }
    if (stg) STAGE_B(T + 3);
    BARRIER();
    __builtin_amdgcn_s_setprio(1);
#pragma unroll
    for (int mi = 0; mi < 4; ++mi)
#pragma unroll
      for (int ni = 0; ni < 4; ++ni)
        acc[4 + mi][ni] = __builtin_amdgcn_mfma_f32_16x16x32_f16(
            af[mi], bg[ni], acc[4 + mi][ni], 0, 0, 0);
    __builtin_amdgcn_s_setprio(0);

    // ---------- K-tile boundary: counted wait (never 0 in steady state) ----
    if (T < NT - 3) {
      asm volatile("s_waitcnt vmcnt(8)" ::: "memory");
    } else if (T == NT - 3) {
      asm volatile("s_waitcnt vmcnt(4)" ::: "memory");
    } else if (T == NT - 2) {
      asm volatile("s_waitcnt vmcnt(0)" ::: "memory");
    }
    BARRIER();
  }

  // ---------- epilogue: out[r][c] = acc * rxn[r] * rwn[c] ----------
  const int ocol = bn + wn * 64 + (lane & 15);
  const int orow0 = bm + wm * 128 + ((lane >> 4) << 2);
  float rw[4];
#pragma unroll
  for (int ni = 0; ni < 4; ++ni) rw[ni] = rwn[ocol + ni * 16];
#pragma unroll
  for (int m = 0; m < 8; ++m) {
#pragma unroll
    for (int jj = 0; jj < 4; ++jj) {
      int r = orow0 + m * 16 + jj;
      float rx = rxn[r];
#pragma unroll
      for (int ni = 0; ni < 4; ++ni)
        out[(size_t)r * N_DIM + ocol + ni * 16] = acc[m][ni][jj] * rx * rw[ni];
    }
  }
#undef STAGE_A
#undef STAGE_B
}

// ---------------------------------------------------------------------------
// fallback (ws too small): fp32 norms + fp32 LDS-tiled GEMM. Correct, slow.
// ---------------------------------------------------------------------------
__global__ __launch_bounds__(256) void fb_norms_kernel(
    const float* __restrict__ x, const float* __restrict__ w,
    float* __restrict__ rxn, float* __restrict__ rwn) {
  int r = blockIdx.x;
  const float* src = (r < M_DIM) ? x + (size_t)r * K_DIM
                                 : w + (size_t)(r - M_DIM) * K_DIM;
  float* rn = (r < M_DIM) ? rxn + r : rwn + (r - M_DIM);
  int tid = threadIdx.x;
  float s = 0.f;
#pragma unroll
  for (int i = 0; i < 4; ++i) {
    int c = (i * 256 + tid) * 4;
    float4 v = *(const float4*)(src + c);
    s += v.x * v.x + v.y * v.y + v.z * v.z + v.w * v.w;
  }
#pragma unroll
  for (int off = 32; off > 0; off >>= 1) s += __shfl_down(s, off);
  __shared__ float red[4];
  if ((tid & 63) == 0) red[tid >> 6] = s;
  __syncthreads();
  if (tid == 0) {
    float t = red[0] + red[1] + red[2] + red[3];
    *rn = 1.0f / fmaxf(sqrtf(t), EPS_F);
  }
}

__global__ __launch_bounds__(256) void fb_gemm_kernel(
    const float* __restrict__ x, const float* __restrict__ w,
    const float* __restrict__ rxn, const float* __restrict__ rwn,
    float* __restrict__ out) {
  __shared__ float As[64][17];
  __shared__ float Bs[64][17];
  int bm = blockIdx.y * 64, bn = blockIdx.x * 64;
  int tid = threadIdx.x;
  int tx = tid & 15, ty = tid >> 4;
  float acc[4][4] = {};
  for (int kt = 0; kt < K_DIM; kt += 16) {
#pragma unroll
    for (int i = 0; i < 4; ++i) {
      int e = i * 256 + tid;
      As[e >> 4][e & 15] = x[(size_t)(bm + (e >> 4)) * K_DIM + kt + (e & 15)];
      Bs[e >> 4][e & 15] = w[(size_t)(bn + (e >> 4)) * K_DIM + kt + (e & 15)];
    }
    __syncthreads();
#pragma unroll
    for (int k = 0; k < 16; ++k)
#pragma unroll
      for (int mi = 0; mi < 4; ++mi)
#pragma unroll
        for (int ni = 0; ni < 4; ++ni)
          acc[mi][ni] += As[ty * 4 + mi][k] * Bs[tx * 4 + ni][k];
    __syncthreads();
  }
#pragma unroll
  for (int mi = 0; mi < 4; ++mi) {
    int r = bm + ty * 4 + mi;
    float rx = rxn[r];
#pragma unroll
    for (int ni = 0; ni < 4; ++ni) {
      int c = bn + tx * 4 + ni;
      out[(size_t)r * N_DIM + c] = acc[mi][ni] * rx * rwn[c];
    }
  }
}

// ---------------------------------------------------------------------------
extern "C" void kernel_launch(void* const* d_in, const int* in_sizes, int n_in,
                              void* d_out, int out_size, void* d_ws, size_t ws_size,
                              hipStream_t stream) {
  const float* x = (const float*)d_in[0];
  const float* w = (const float*)d_in[1];
  float* out = (float*)d_out;
  char* ws = (char*)d_ws;

  float* rxn = (float*)ws;                      // 16 KiB
  float* rwn = (float*)(ws + (16 << 10));       // 32 KiB
  float* partials = (float*)(ws + (64 << 10));  // 192 KiB (12288 rows x 4)
  const size_t base = 256 << 10;
  const size_t xelems = (size_t)M_DIM * K_DIM;  // 16M
  const size_t welems = (size_t)N_DIM * K_DIM;  // 32M
  const size_t need = base + (xelems + welems) * sizeof(_Float16);

  if (ws_size >= need) {
    _Float16* xh = (_Float16*)(ws + base);
    _Float16* wh = xh + xelems;
    prep_kernel<<<M_DIM + N_DIM, 256, 0, stream>>>(x, w, xh, wh, partials);
    finalize_kernel<<<(M_DIM + N_DIM) / 256, 256, 0, stream>>>(partials, rxn,
                                                               rwn);
    gemm_cos_kernel<<<512, 512, 0, stream>>>(xh, wh, rxn, rwn, out);
  } else {
    fb_norms_kernel<<<M_DIM + N_DIM, 256, 0, stream>>>(x, w, rxn, rwn);
    fb_gemm_kernel<<<dim3(N_DIM / 64, M_DIM / 64), 256, 0, stream>>>(
        x, w, rxn, rwn, out);
  }
}

// Round 8
// 524.395 us; speedup vs baseline: 2.6580x; 1.0078x over previous
//
#include <hip/hip_runtime.h>
#include <hip/hip_bf16.h>
#include <stdint.h>

#define M_DIM 4096
#define N_DIM 8192
#define K_DIM 4096
#define EPS_F 1e-8f

typedef __attribute__((ext_vector_type(8))) _Float16 f16x8;
typedef __attribute__((ext_vector_type(4))) _Float16 f16x4;
typedef __attribute__((ext_vector_type(4))) float f32x4;

// async global->LDS, 16B per lane. LDS dest must be linear: wave base + lane*16.
#define GLD16(g, l) __builtin_amdgcn_global_load_lds( \
    (const __attribute__((address_space(1))) void*)(g), \
    (__attribute__((address_space(3))) void*)(l), 16, 0, 0)

// raw barrier (no vmcnt drain) + compiler-only memory fence so LDS ops can't
// be reordered across it (llvm.amdgcn.s.barrier is not an IR memory fence).
#define BARRIER() do { asm volatile("" ::: "memory"); \
  __builtin_amdgcn_s_barrier(); asm volatile("" ::: "memory"); } while (0)

// ---------------------------------------------------------------------------
// prep: one block per row (4096 x-rows then 8192 w-rows). Each WAVE covers a
// quarter-row independently. [UNCHANGED from round 5]
// ---------------------------------------------------------------------------
__global__ __launch_bounds__(256) void prep_kernel(
    const float* __restrict__ x, const float* __restrict__ w,
    _Float16* __restrict__ xh, _Float16* __restrict__ wh,
    float* __restrict__ partials) {
  int r = blockIdx.x;
  const float* src;
  _Float16* dst;
  if (r < M_DIM) {
    src = x + (size_t)r * K_DIM;
    dst = xh + (size_t)r * K_DIM;
  } else {
    int rr = r - M_DIM;
    src = w + (size_t)rr * K_DIM;
    dst = wh + (size_t)rr * K_DIM;
  }
  const int lane = threadIdx.x & 63;
  const int wv = threadIdx.x >> 6;
  const int base = wv * 1024;
  float s = 0.f;
#pragma unroll
  for (int i = 0; i < 4; ++i) {
    int c = base + i * 256 + lane * 4;
    float4 v = *(const float4*)(src + c);
    s += v.x * v.x + v.y * v.y + v.z * v.z + v.w * v.w;
    f16x4 h;
    h[0] = (_Float16)v.x; h[1] = (_Float16)v.y;
    h[2] = (_Float16)v.z; h[3] = (_Float16)v.w;
    *(f16x4*)(dst + c) = h;
  }
#pragma unroll
  for (int off = 32; off > 0; off >>= 1) s += __shfl_down(s, off);
  if (lane == 0) partials[r * 4 + wv] = s;
}

// finalize: rn[r] = 1/max(sqrt(sum of 4 partials), eps). 12288 threads.
__global__ __launch_bounds__(256) void finalize_kernel(
    const float* __restrict__ partials,
    float* __restrict__ rxn, float* __restrict__ rwn) {
  int r = blockIdx.x * 256 + threadIdx.x;
  f32x4 p = *(const f32x4*)(partials + (size_t)r * 4);
  float t = p[0] + p[1] + p[2] + p[3];
  float v = 1.0f / fmaxf(sqrtf(t), EPS_F);
  if (r < M_DIM) rxn[r] = v;
  else rwn[r - M_DIM] = v;
}

// ---------------------------------------------------------------------------
// GEMM: 256x256 tile, BK=64, 2 LDS buffers (A/B each split in 2 K-slices),
// 8 waves (2M x 4N), 4 phases per K-tile (quadrant = M-half x K-slice),
// 1 half-unit staged per phase, vmcnt(4) once per K-tile, setprio on MFMA.
//
// LDS map (per buffer, 64KB): A-ks0[256x64B] A-ks1 B-ks0 B-ks1 (16KB each).
// Swizzle (measured conflict-free in r5): phys chunk p = j16 ^ ((row>>1)&3).
// Stage schedule (derived; deadlines guaranteed by vmcnt(4) at each ph4):
//   ph1: stage A-ks1(T+1)   ph2: stage B-ks1(T+1)
//   ph3: stage A-ks0(T+2)   ph4: stage B-ks0(T+2), vmcnt(4)
// Each overwritten slot's last ds_read is >=1 barrier before its stage.
// ---------------------------------------------------------------------------
__global__ __launch_bounds__(512, 2) void gemm_cos_kernel(
    const _Float16* __restrict__ xh, const _Float16* __restrict__ wh,
    const float* __restrict__ rxn, const float* __restrict__ rwn,
    float* __restrict__ out) {
  __shared__ __align__(16) char lds[131072];

  const int tid = threadIdx.x;
  const int lane = tid & 63;
  const int wid = tid >> 6;
  const int wm = wid >> 2;  // 0..1  (M half: 128 rows)
  const int wn = wid & 3;   // 0..3  (N quarter: 64 cols)

  int bid = blockIdx.x;
  int swz = (bid & 7) * 64 + (bid >> 3);  // 512 blocks, 8 XCDs, bijective
  const int bm = (swz >> 5) << 8;  // 16 M-tiles
  const int bn = (swz & 31) << 8;  // 32 N-tiles

  // ---- staging geometry: unit = 256 rows x 32 k (16KB), 2 GLD16/thread.
  // thread t, load L: phys row = L*128 + (t>>2), phys chunk = t&3;
  // global chunk j_g = (t&3) ^ ((t>>3)&3)  (inverse of read swizzle).
  const int srow = tid >> 2;
  const int jg = (tid & 3) ^ ((tid >> 3) & 3);
  const size_t aoff0 = (size_t)(bm + srow) * K_DIM + jg * 8;
  const size_t aoff1 = (size_t)(bm + 128 + srow) * K_DIM + jg * 8;
  const size_t boff0 = (size_t)(bn + srow) * K_DIM + jg * 8;
  const size_t boff1 = (size_t)(bn + 128 + srow) * K_DIM + jg * 8;

  // ---- read geometry: row r, k-chunk j16=lane>>4 within a k-slice
  const int j16 = lane >> 4;
  const int arb = wm * 128 + (lane & 15);
  const int brb = wn * 64 + (lane & 15);

  f32x4 acc[8][4] = {};
  const int NT = K_DIM / 64;  // 64

  // STAGE one unit: operand ptr/offsets, tile s_, k-slice ks_, isB selects slot
#define STAGE(ptr, off0, off1, s_, ks_, isB) do { \
    char* d_ = lds + (size_t)((s_) & 1) * 65536 + (isB) * 32768 + \
               (ks_) * 16384 + tid * 16; \
    size_t g_ = (size_t)(s_) * 64 + (ks_) * 32; \
    GLD16(ptr + off0 + g_, d_); \
    GLD16(ptr + off1 + g_, d_ + 8192); } while (0)

#define LDSWZ(base_, r_) ((base_) + (r_) * 64 + ((j16 ^ (((r_) >> 1) & 3)) << 4))

  // prologue: tile0 (4 units) + A-ks0,B-ks0 of tile1; wait so tile0 landed.
  STAGE(xh, aoff0, aoff1, 0, 0, 0);
  STAGE(wh, boff0, boff1, 0, 0, 1);
  STAGE(xh, aoff0, aoff1, 0, 1, 0);
  STAGE(wh, boff0, boff1, 0, 1, 1);
  STAGE(xh, aoff0, aoff1, 1, 0, 0);
  STAGE(wh, boff0, boff1, 1, 0, 1);
  asm volatile("s_waitcnt vmcnt(4)" ::: "memory");
  BARRIER();

  for (int T = 0; T < NT; ++T) {
    char* const bufb = lds + (size_t)(T & 1) * 65536;
    f16x8 af[4], bg[4];

    // ---------------- phase 1: ks0, M-quad0 (reads A+B) ----------------
    {
      char* ab = bufb;            // A-ks0
      char* bb = bufb + 32768;    // B-ks0
#pragma unroll
      for (int mi = 0; mi < 4; ++mi) {
        int r = arb + mi * 16;
        af[mi] = *(const f16x8*)LDSWZ(ab, r);
      }
#pragma unroll
      for (int ni = 0; ni < 4; ++ni) {
        int r = brb + ni * 16;
        bg[ni] = *(const f16x8*)LDSWZ(bb, r);
      }
      if (T + 1 < NT) STAGE(xh, aoff0, aoff1, T + 1, 1, 0);
      BARRIER();
      asm volatile("s_waitcnt lgkmcnt(0)" ::: "memory");
      __builtin_amdgcn_sched_barrier(0);
      __builtin_amdgcn_s_setprio(1);
#pragma unroll
      for (int mi = 0; mi < 4; ++mi)
#pragma unroll
        for (int ni = 0; ni < 4; ++ni)
          acc[mi][ni] = __builtin_amdgcn_mfma_f32_16x16x32_f16(
              af[mi], bg[ni], acc[mi][ni], 0, 0, 0);
      __builtin_amdgcn_s_setprio(0);
      BARRIER();
    }

    // ---------------- phase 2: ks0, M-quad1 (B reused) ----------------
    {
      char* ab = bufb;
#pragma unroll
      for (int mi = 0; mi < 4; ++mi) {
        int r = arb + 64 + mi * 16;
        af[mi] = *(const f16x8*)LDSWZ(ab, r);
      }
      if (T + 1 < NT) STAGE(wh, boff0, boff1, T + 1, 1, 1);
      BARRIER();
      asm volatile("s_waitcnt lgkmcnt(0)" ::: "memory");
      __builtin_amdgcn_sched_barrier(0);
      __builtin_amdgcn_s_setprio(1);
#pragma unroll
      for (int mi = 0; mi < 4; ++mi)
#pragma unroll
        for (int ni = 0; ni < 4; ++ni)
          acc[4 + mi][ni] = __builtin_amdgcn_mfma_f32_16x16x32_f16(
              af[mi], bg[ni], acc[4 + mi][ni], 0, 0, 0);
      __builtin_amdgcn_s_setprio(0);
      BARRIER();
    }

    // ---------------- phase 3: ks1, M-quad0 (reads A+B) ----------------
    {
      char* ab = bufb + 16384;    // A-ks1
      char* bb = bufb + 49152;    // B-ks1
#pragma unroll
      for (int mi = 0; mi < 4; ++mi) {
        int r = arb + mi * 16;
        af[mi] = *(const f16x8*)LDSWZ(ab, r);
      }
#pragma unroll
      for (int ni = 0; ni < 4; ++ni) {
        int r = brb + ni * 16;
        bg[ni] = *(const f16x8*)LDSWZ(bb, r);
      }
      if (T + 2 < NT) STAGE(xh, aoff0, aoff1, T + 2, 0, 0);
      BARRIER();
      asm volatile("s_waitcnt lgkmcnt(0)" ::: "memory");
      __builtin_amdgcn_sched_barrier(0);
      __builtin_amdgcn_s_setprio(1);
#pragma unroll
      for (int mi = 0; mi < 4; ++mi)
#pragma unroll
        for (int ni = 0; ni < 4; ++ni)
          acc[mi][ni] = __builtin_amdgcn_mfma_f32_16x16x32_f16(
              af[mi], bg[ni], acc[mi][ni], 0, 0, 0);
      __builtin_amdgcn_s_setprio(0);
      BARRIER();
    }

    // ---------------- phase 4: ks1, M-quad1 + counted vmcnt ----------------
    {
      char* ab = bufb + 16384;
#pragma unroll
      for (int mi = 0; mi < 4; ++mi) {
        int r = arb + 64 + mi * 16;
        af[mi] = *(const f16x8*)LDSWZ(ab, r);
      }
      if (T + 2 < NT) {
        STAGE(wh, boff0, boff1, T + 2, 0, 1);
        asm volatile("s_waitcnt vmcnt(4)" ::: "memory");
      } else {
        asm volatile("s_waitcnt vmcnt(0)" ::: "memory");
      }
      BARRIER();
      asm volatile("s_waitcnt lgkmcnt(0)" ::: "memory");
      __builtin_amdgcn_sched_barrier(0);
      __builtin_amdgcn_s_setprio(1);
#pragma unroll
      for (int mi = 0; mi < 4; ++mi)
#pragma unroll
        for (int ni = 0; ni < 4; ++ni)
          acc[4 + mi][ni] = __builtin_amdgcn_mfma_f32_16x16x32_f16(
              af[mi], bg[ni], acc[4 + mi][ni], 0, 0, 0);
      __builtin_amdgcn_s_setprio(0);
      BARRIER();
    }
  }

  // ---------- epilogue: out[r][c] = acc * rxn[r] * rwn[c] ----------
  const int ocol = bn + wn * 64 + (lane & 15);
  const int orow0 = bm + wm * 128 + ((lane >> 4) << 2);
  float rw[4];
#pragma unroll
  for (int ni = 0; ni < 4; ++ni) rw[ni] = rwn[ocol + ni * 16];
#pragma unroll
  for (int m = 0; m < 8; ++m) {
#pragma unroll
    for (int jj = 0; jj < 4; ++jj) {
      int r = orow0 + m * 16 + jj;
      float rx = rxn[r];
#pragma unroll
      for (int ni = 0; ni < 4; ++ni)
        out[(size_t)r * N_DIM + ocol + ni * 16] = acc[m][ni][jj] * rx * rw[ni];
    }
  }
#undef STAGE
#undef LDSWZ
}

// ---------------------------------------------------------------------------
// fallback (ws too small): fp32 norms + fp32 LDS-tiled GEMM. Correct, slow.
// ---------------------------------------------------------------------------
__global__ __launch_bounds__(256) void fb_norms_kernel(
    const float* __restrict__ x, const float* __restrict__ w,
    float* __restrict__ rxn, float* __restrict__ rwn) {
  int r = blockIdx.x;
  const float* src = (r < M_DIM) ? x + (size_t)r * K_DIM
                                 : w + (size_t)(r - M_DIM) * K_DIM;
  float* rn = (r < M_DIM) ? rxn + r : rwn + (r - M_DIM);
  int tid = threadIdx.x;
  float s = 0.f;
#pragma unroll
  for (int i = 0; i < 4; ++i) {
    int c = (i * 256 + tid) * 4;
    float4 v = *(const float4*)(src + c);
    s += v.x * v.x + v.y * v.y + v.z * v.z + v.w * v.w;
  }
#pragma unroll
  for (int off = 32; off > 0; off >>= 1) s += __shfl_down(s, off);
  __shared__ float red[4];
  if ((tid & 63) == 0) red[tid >> 6] = s;
  __syncthreads();
  if (tid == 0) {
    float t = red[0] + red[1] + red[2] + red[3];
    *rn = 1.0f / fmaxf(sqrtf(t), EPS_F);
  }
}

__global__ __launch_bounds__(256) void fb_gemm_kernel(
    const float* __restrict__ x, const float* __restrict__ w,
    const float* __restrict__ rxn, const float* __restrict__ rwn,
    float* __restrict__ out) {
  __shared__ float As[64][17];
  __shared__ float Bs[64][17];
  int bm = blockIdx.y * 64, bn = blockIdx.x * 64;
  int tid = threadIdx.x;
  int tx = tid & 15, ty = tid >> 4;
  float acc[4][4] = {};
  for (int kt = 0; kt < K_DIM; kt += 16) {
#pragma unroll
    for (int i = 0; i < 4; ++i) {
      int e = i * 256 + tid;
      As[e >> 4][e & 15] = x[(size_t)(bm + (e >> 4)) * K_DIM + kt + (e & 15)];
      Bs[e >> 4][e & 15] = w[(size_t)(bn + (e >> 4)) * K_DIM + kt + (e & 15)];
    }
    __syncthreads();
#pragma unroll
    for (int k = 0; k < 16; ++k)
#pragma unroll
      for (int mi = 0; mi < 4; ++mi)
#pragma unroll
        for (int ni = 0; ni < 4; ++ni)
          acc[mi][ni] += As[ty * 4 + mi][k] * Bs[tx * 4 + ni][k];
    __syncthreads();
  }
#pragma unroll
  for (int mi = 0; mi < 4; ++mi) {
    int r = bm + ty * 4 + mi;
    float rx = rxn[r];
#pragma unroll
    for (int ni = 0; ni < 4; ++ni) {
      int c = bn + tx * 4 + ni;
      out[(size_t)r * N_DIM + c] = acc[mi][ni] * rx * rwn[c];
    }
  }
}

// ---------------------------------------------------------------------------
extern "C" void kernel_launch(void* const* d_in, const int* in_sizes, int n_in,
                              void* d_out, int out_size, void* d_ws, size_t ws_size,
                              hipStream_t stream) {
  const float* x = (const float*)d_in[0];
  const float* w = (const float*)d_in[1];
  float* out = (float*)d_out;
  char* ws = (char*)d_ws;

  float* rxn = (float*)ws;                      // 16 KiB
  float* rwn = (float*)(ws + (16 << 10));       // 32 KiB
  float* partials = (float*)(ws + (64 << 10));  // 192 KiB (12288 rows x 4)
  const size_t base = 256 << 10;
  const size_t xelems = (size_t)M_DIM * K_DIM;  // 16M
  const size_t welems = (size_t)N_DIM * K_DIM;  // 32M
  const size_t need = base + (xelems + welems) * sizeof(_Float16);

  if (ws_size >= need) {
    _Float16* xh = (_Float16*)(ws + base);
    _Float16* wh = xh + xelems;
    prep_kernel<<<M_DIM + N_DIM, 256, 0, stream>>>(x, w, xh, wh, partials);
    finalize_kernel<<<(M_DIM + N_DIM) / 256, 256, 0, stream>>>(partials, rxn,
                                                               rwn);
    gemm_cos_kernel<<<512, 512, 0, stream>>>(xh, wh, rxn, rwn, out);
  } else {
    fb_norms_kernel<<<M_DIM + N_DIM, 256, 0, stream>>>(x, w, rxn, rwn);
    fb_gemm_kernel<<<dim3(N_DIM / 64, M_DIM / 64), 256, 0, stream>>>(
        x, w, rxn, rwn, out);
  }
}